// Round 3
// baseline (559.733 us; speedup 1.0000x reference)
//
#include <hip/hip_runtime.h>
#include <hip/hip_bf16.h>
#include <math.h>

static inline size_t align_up(size_t x, size_t a) { return (x + a - 1) / a * a; }

typedef short bf16x8 __attribute__((ext_vector_type(8)));
typedef float f32x4 __attribute__((ext_vector_type(4)));

// ---------------- CSR build ----------------

__global__ void hist_kernel(const int* __restrict__ dst, int* __restrict__ cnt, int e) {
  int i = blockIdx.x * blockDim.x + threadIdx.x;
  if (i < e) atomicAdd(&cnt[dst[i]], 1);
}

__global__ __launch_bounds__(256) void scanA_kernel(const int* __restrict__ cnt,
                                                    int* __restrict__ excl,
                                                    int* __restrict__ bsum, int n) {
  __shared__ int sm[256];
  int gi = blockIdx.x * 256 + threadIdx.x;
  int v = (gi < n) ? cnt[gi] : 0;
  sm[threadIdx.x] = v;
  __syncthreads();
  for (int off = 1; off < 256; off <<= 1) {
    int x = (threadIdx.x >= off) ? sm[threadIdx.x - off] : 0;
    __syncthreads();
    sm[threadIdx.x] += x;
    __syncthreads();
  }
  if (gi < n) excl[gi] = sm[threadIdx.x] - v;
  if (threadIdx.x == 255) bsum[blockIdx.x] = sm[255];
}

__global__ __launch_bounds__(512) void scanB_kernel(int* __restrict__ bsum, int nb) {
  __shared__ int sm[512];
  const int t = threadIdx.x;
  int v = (t < nb) ? bsum[t] : 0;
  sm[t] = v;
  __syncthreads();
  for (int off = 1; off < 512; off <<= 1) {
    int x = (t >= off) ? sm[t - off] : 0;
    __syncthreads();
    sm[t] += x;
    __syncthreads();
  }
  if (t < nb) bsum[t] = sm[t] - v;  // exclusive block offsets
}

__global__ void scanC_kernel(int* __restrict__ rowptr, const int* __restrict__ bsum,
                             int n, int e) {
  int gi = blockIdx.x * 256 + threadIdx.x;
  if (gi < n) rowptr[gi] += bsum[blockIdx.x];
  if (gi == 0) rowptr[n] = e;
}

__global__ void dinv_kernel(const int* __restrict__ rowptr, float* __restrict__ dinv, int n) {
  int gi = blockIdx.x * blockDim.x + threadIdx.x;
  if (gi < n) dinv[gi] = rsqrtf((float)(rowptr[gi + 1] - rowptr[gi] + 1));
}

__global__ void fill_kernel(const int* __restrict__ src, const int* __restrict__ dst,
                            const int* __restrict__ rowptr, int* __restrict__ cur,
                            const float* __restrict__ dinv, int* __restrict__ ssrc,
                            float* __restrict__ wnorm, int e) {
  int i = blockIdx.x * blockDim.x + threadIdx.x;
  if (i < e) {
    int d = dst[i];
    int s = src[i];
    int pos = rowptr[d] + atomicAdd(&cur[d], 1);
    ssrc[pos] = s;
    wnorm[pos] = dinv[s] * dinv[d];
  }
}

// ---------------- split-bf16 helpers ----------------

__device__ __forceinline__ void bf16_split(float x, unsigned short& hi, unsigned short& lo) {
  unsigned u = __float_as_uint(x);
  unsigned r = (u + 0x7fffu + ((u >> 16) & 1u)) & 0xffff0000u;
  hi = (unsigned short)(r >> 16);
  float rem = x - __uint_as_float(r);
  unsigned u2 = __float_as_uint(rem);
  unsigned r2 = u2 + 0x7fffu + ((u2 >> 16) & 1u);
  lo = (unsigned short)(r2 >> 16);
}

// Pack W[K][128] fp32 into MFMA B-fragment order, split hi/lo bf16.
// Entry (k,n): flat = (((k>>5)*128 + n)*4 + ((k>>3)&3))*8 + (k&7)
__global__ void wsplit_kernel(const float* __restrict__ W,
                              unsigned short* __restrict__ whi,
                              unsigned short* __restrict__ wlo, int total) {
  int i = blockIdx.x * blockDim.x + threadIdx.x;
  if (i >= total) return;
  int k = i >> 7;
  int n = i & 127;
  unsigned short h, l;
  bf16_split(W[i], h, l);
  size_t idx = ((size_t)(((k >> 5) * 128 + n) * 4 + ((k >> 3) & 3)) << 3) + (k & 7);
  whi[idx] = h;
  wlo[idx] = l;
}

// ---------------- GEMM via split-bf16 MFMA ----------------
// out[N][128] = A(concat x|emb[drnl], or z)[N][K] @ W[K][128]
// block: 64 rows x 128 cols, 4 waves, wave w -> rows w*16..w*16+15, all cols.

__global__ __launch_bounds__(256) void gemm_mfma_kernel(
    const float* __restrict__ A, const float* __restrict__ emb,
    const int* __restrict__ drnl,
    const unsigned short* __restrict__ whi, const unsigned short* __restrict__ wlo,
    float* __restrict__ out, int n, int K) {
  __shared__ unsigned short Ah[64][168];  // row stride 168 shorts = 84 dwords -> 2-way banks (free)
  __shared__ unsigned short Al[64][168];
  const int tid = threadIdx.x;
  const int row0 = blockIdx.x * 64;
  const int Kq = K >> 2;  // float4s per row

  for (int i = tid; i < (K << 4); i += 256) {  // 64*K/4 elems
    const int row = i / Kq;
    const int c4 = i - row * Kq;
    const int col = c4 << 2;
    float4 v = make_float4(0.f, 0.f, 0.f, 0.f);
    const int grow = row0 + row;
    if (grow < n) {
      if (col < 128) v = *(const float4*)(A + (size_t)grow * 128 + col);
      else v = *(const float4*)(emb + (size_t)drnl[grow] * 32 + (col - 128));
    }
    unsigned short h0, l0, h1, l1, h2, l2, h3, l3;
    bf16_split(v.x, h0, l0);
    bf16_split(v.y, h1, l1);
    bf16_split(v.z, h2, l2);
    bf16_split(v.w, h3, l3);
    ushort4 hv; hv.x = h0; hv.y = h1; hv.z = h2; hv.w = h3;
    ushort4 lv; lv.x = l0; lv.y = l1; lv.z = l2; lv.w = l3;
    *(ushort4*)&Ah[row][col] = hv;
    *(ushort4*)&Al[row][col] = lv;
  }
  __syncthreads();

  const int w = tid >> 6;
  const int l = tid & 63;
  const int r = l & 15;
  const int q = l >> 4;

  f32x4 acc[8];
#pragma unroll
  for (int ct = 0; ct < 8; ++ct) {
    acc[ct][0] = 0.f; acc[ct][1] = 0.f; acc[ct][2] = 0.f; acc[ct][3] = 0.f;
  }

  const int nks = K >> 5;
  for (int ks = 0; ks < nks; ++ks) {
    const int kb = (ks << 5) + (q << 3);
    const bf16x8 ah = *(const bf16x8*)&Ah[(w << 4) + r][kb];
    const bf16x8 al = *(const bf16x8*)&Al[(w << 4) + r][kb];
#pragma unroll
    for (int ct = 0; ct < 8; ++ct) {
      const size_t off = ((size_t)((((ks << 7) + (ct << 4) + r) << 2) + q)) << 3;
      const bf16x8 bh = *(const bf16x8*)(whi + off);
      const bf16x8 bl = *(const bf16x8*)(wlo + off);
      acc[ct] = __builtin_amdgcn_mfma_f32_16x16x32_bf16(ah, bh, acc[ct], 0, 0, 0);
      acc[ct] = __builtin_amdgcn_mfma_f32_16x16x32_bf16(al, bh, acc[ct], 0, 0, 0);
      acc[ct] = __builtin_amdgcn_mfma_f32_16x16x32_bf16(ah, bl, acc[ct], 0, 0, 0);
    }
  }

#pragma unroll
  for (int ct = 0; ct < 8; ++ct) {
#pragma unroll
    for (int j = 0; j < 4; ++j) {
      const int grow = row0 + (w << 4) + (q << 2) + j;
      if (grow < n) out[(size_t)grow * 128 + (ct << 4) + r] = acc[ct][j];
    }
  }
}

// ---------------- Aggregation: one wave per node, pull over CSR (unroll 8) ----------------

__global__ __launch_bounds__(256) void agg_kernel(
    const float* __restrict__ hw, const int* __restrict__ rowptr,
    const int* __restrict__ ssrc, const float* __restrict__ wnorm,
    const float* __restrict__ dinv, const float* __restrict__ bias,
    float* __restrict__ out, int n) {
  const int widx = (blockIdx.x * blockDim.x + threadIdx.x) >> 6;
  if (widx >= n) return;
  const int wid = __builtin_amdgcn_readfirstlane(widx);
  const int lane = threadIdx.x & 63;
  const int start = rowptr[wid];
  const int end = rowptr[wid + 1];
  const float2* __restrict__ hw2 = (const float2*)hw;
  float ax = 0.f, ay = 0.f;
  int e = start;
  for (; e + 8 <= end; e += 8) {
    const int s0 = ssrc[e + 0];
    const int s1 = ssrc[e + 1];
    const int s2 = ssrc[e + 2];
    const int s3 = ssrc[e + 3];
    const int s4 = ssrc[e + 4];
    const int s5 = ssrc[e + 5];
    const int s6 = ssrc[e + 6];
    const int s7 = ssrc[e + 7];
    const float n0 = wnorm[e + 0];
    const float n1 = wnorm[e + 1];
    const float n2 = wnorm[e + 2];
    const float n3 = wnorm[e + 3];
    const float n4 = wnorm[e + 4];
    const float n5 = wnorm[e + 5];
    const float n6 = wnorm[e + 6];
    const float n7 = wnorm[e + 7];
    const float2 v0 = hw2[(size_t)s0 * 64 + lane];
    const float2 v1 = hw2[(size_t)s1 * 64 + lane];
    const float2 v2 = hw2[(size_t)s2 * 64 + lane];
    const float2 v3 = hw2[(size_t)s3 * 64 + lane];
    const float2 v4 = hw2[(size_t)s4 * 64 + lane];
    const float2 v5 = hw2[(size_t)s5 * 64 + lane];
    const float2 v6 = hw2[(size_t)s6 * 64 + lane];
    const float2 v7 = hw2[(size_t)s7 * 64 + lane];
    ax = fmaf(v0.x, n0, ax); ay = fmaf(v0.y, n0, ay);
    ax = fmaf(v1.x, n1, ax); ay = fmaf(v1.y, n1, ay);
    ax = fmaf(v2.x, n2, ax); ay = fmaf(v2.y, n2, ay);
    ax = fmaf(v3.x, n3, ax); ay = fmaf(v3.y, n3, ay);
    ax = fmaf(v4.x, n4, ax); ay = fmaf(v4.y, n4, ay);
    ax = fmaf(v5.x, n5, ax); ay = fmaf(v5.y, n5, ay);
    ax = fmaf(v6.x, n6, ax); ay = fmaf(v6.y, n6, ay);
    ax = fmaf(v7.x, n7, ax); ay = fmaf(v7.y, n7, ay);
  }
  for (; e < end; ++e) {
    const int s = ssrc[e];
    const float nm = wnorm[e];
    const float2 v = hw2[(size_t)s * 64 + lane];
    ax = fmaf(v.x, nm, ax);
    ay = fmaf(v.y, nm, ay);
  }
  const float di = dinv[wid];
  const float ww = di * di;
  const float2 sv = hw2[(size_t)wid * 64 + lane];
  ax = fmaf(sv.x, ww, ax);
  ay = fmaf(sv.y, ww, ay);
  const float2 bb = ((const float2*)bias)[lane];
  float ox = ax + bb.x, oy = ay + bb.y;
  float2 o;
  o.x = ox > 0.f ? ox : 0.f;
  o.y = oy > 0.f ? oy : 0.f;
  ((float2*)out)[(size_t)wid * 64 + lane] = o;
}

// ---------------- Pool: segment max (contiguous segments of NPG rows) ----------------

__global__ __launch_bounds__(128) void pool_kernel(const float* __restrict__ z,
                                                   float* __restrict__ pool, int npg) {
  const int g = blockIdx.x;
  const int c = threadIdx.x;
  const float* base = z + (size_t)g * npg * 128;
  float m = -INFINITY;
  for (int r = 0; r < npg; ++r) m = fmaxf(m, base[(size_t)r * 128 + c]);
  pool[(size_t)g * 128 + c] = m;
}

// ---------------- Head MLP: one block (128 threads) per graph ----------------

__global__ __launch_bounds__(128) void final_kernel(
    const float* __restrict__ z, const float* __restrict__ pool,
    const int* __restrict__ tloc, const int* __restrict__ ptr,
    const float* __restrict__ Wm1, const float* __restrict__ bm1,
    const float* __restrict__ Wm2, const float* __restrict__ bm2,
    float* __restrict__ out) {
  __shared__ float feats[640];
  __shared__ float hid[128];
  const int g = blockIdx.x;
  const int t = threadIdx.x;
  const int base = ptr[g];
  const int u = base + tloc[2 * g];
  const int v = base + tloc[2 * g + 1];
  const float hu = z[(size_t)u * 128 + t];
  const float hv = z[(size_t)v * 128 + t];
  feats[t] = hu;
  feats[128 + t] = hv;
  feats[256 + t] = fabsf(hu - hv);
  feats[384 + t] = hu * hv;
  feats[512 + t] = pool[(size_t)g * 128 + t];
  __syncthreads();
  float acc = bm1[t];
#pragma unroll 8
  for (int k = 0; k < 640; ++k) acc = fmaf(feats[k], Wm1[(size_t)k * 128 + t], acc);
  hid[t] = acc > 0.f ? acc : 0.f;
  __syncthreads();
  if (t < 2) {
    float a = bm2[t];
    for (int j = 0; j < 128; ++j) a = fmaf(hid[j], Wm2[j * 2 + t], a);
    out[g * 2 + t] = a;
  }
}

// ---------------- launch ----------------

extern "C" void kernel_launch(void* const* d_in, const int* in_sizes, int n_in,
                              void* d_out, int out_size, void* d_ws, size_t ws_size,
                              hipStream_t stream) {
  const float* x   = (const float*)d_in[0];
  const float* emb = (const float*)d_in[1];
  const float* W1  = (const float*)d_in[2];
  const float* b1  = (const float*)d_in[3];
  const float* W2  = (const float*)d_in[4];
  const float* b2  = (const float*)d_in[5];
  const float* Wm1 = (const float*)d_in[6];
  const float* bm1 = (const float*)d_in[7];
  const float* Wm2 = (const float*)d_in[8];
  const float* bm2 = (const float*)d_in[9];
  const int* eidx  = (const int*)d_in[10];
  const int* drnl  = (const int*)d_in[11];
  const int* tloc  = (const int*)d_in[13];
  const int* ptr   = (const int*)d_in[14];
  float* out = (float*)d_out;

  const int N = in_sizes[11];
  const int E = in_sizes[10] / 2;
  const int G = in_sizes[13] / 2;
  const int NPG = N / G;
  const int* srcp = eidx;
  const int* dstp = eidx + E;

  char* w = (char*)d_ws;
  size_t o = 0;
  auto alloc = [&](size_t bytes) {
    void* p = w + o;
    o = align_up(o + bytes, 256);
    return p;
  };
  int*   rowptr = (int*)alloc((size_t)(N + 1) * 4);
  int*   cnt    = (int*)alloc((size_t)N * 4);
  int*   bsum   = (int*)alloc(4096);
  float* dinv   = (float*)alloc((size_t)N * 4);
  int*   ssrc   = (int*)alloc((size_t)E * 4);
  float* wnorm  = (float*)alloc((size_t)E * 4);
  float* hw     = (float*)alloc((size_t)N * 128 * 4);
  float* zb     = (float*)alloc((size_t)N * 128 * 4);
  float* poolb  = (float*)alloc((size_t)G * 128 * 4);
  unsigned short* w1hi = (unsigned short*)alloc((size_t)160 * 128 * 2);
  unsigned short* w1lo = (unsigned short*)alloc((size_t)160 * 128 * 2);
  unsigned short* w2hi = (unsigned short*)alloc((size_t)128 * 128 * 2);
  unsigned short* w2lo = (unsigned short*)alloc((size_t)128 * 128 * 2);

  const int nbN = (N + 255) / 256;
  const int nbE = (E + 255) / 256;

  hipMemsetAsync(cnt, 0, (size_t)N * 4, stream);
  hist_kernel<<<nbE, 256, 0, stream>>>(dstp, cnt, E);
  scanA_kernel<<<nbN, 256, 0, stream>>>(cnt, rowptr, bsum, N);
  scanB_kernel<<<1, 512, 0, stream>>>(bsum, nbN);
  scanC_kernel<<<nbN, 256, 0, stream>>>(rowptr, bsum, N, E);
  dinv_kernel<<<nbN, 256, 0, stream>>>(rowptr, dinv, N);
  hipMemsetAsync(cnt, 0, (size_t)N * 4, stream);
  fill_kernel<<<nbE, 256, 0, stream>>>(srcp, dstp, rowptr, cnt, dinv, ssrc, wnorm, E);

  wsplit_kernel<<<(160 * 128 + 255) / 256, 256, 0, stream>>>(W1, w1hi, w1lo, 160 * 128);
  wsplit_kernel<<<(128 * 128 + 255) / 256, 256, 0, stream>>>(W2, w2hi, w2lo, 128 * 128);

  gemm_mfma_kernel<<<(N + 63) / 64, 256, 0, stream>>>(x, emb, drnl, w1hi, w1lo, hw, N, 160);
  agg_kernel<<<(N * 64 + 255) / 256, 256, 0, stream>>>(hw, rowptr, ssrc, wnorm, dinv, b1, zb, N);
  gemm_mfma_kernel<<<(N + 63) / 64, 256, 0, stream>>>(zb, emb, drnl, w2hi, w2lo, hw, N, 128);
  agg_kernel<<<(N * 64 + 255) / 256, 256, 0, stream>>>(hw, rowptr, ssrc, wnorm, dinv, b2, zb, N);
  pool_kernel<<<G, 128, 0, stream>>>(zb, poolb, NPG);
  final_kernel<<<G, 128, 0, stream>>>(zb, poolb, tloc, ptr, Wm1, bm1, Wm2, bm2, out);
}